// Round 1
// baseline (256.715 us; speedup 1.0000x reference)
//
#include <hip/hip_runtime.h>
#include <hip/hip_bf16.h>

#define D 64

// ---- kernel 1: histogram counts[dst[e]]++ ----
__global__ void count_kernel(const int* __restrict__ dst, int* __restrict__ counts, int E) {
    int e = blockIdx.x * blockDim.x + threadIdx.x;
    if (e < E) atomicAdd(&counts[dst[e]], 1);
}

// ---- kernel 2: single-block exclusive scan over counts -> offsets, cursor ----
__global__ void scan_kernel(const int* __restrict__ counts, int* __restrict__ offsets,
                            int* __restrict__ cursor, int N) {
    __shared__ int tmp[1024];
    int t = threadIdx.x;
    int carry = 0;
    for (int base = 0; base < N; base += 1024) {
        int i = base + t;
        int v = (i < N) ? counts[i] : 0;
        tmp[t] = v;
        __syncthreads();
        #pragma unroll
        for (int off = 1; off < 1024; off <<= 1) {
            int x = (t >= off) ? tmp[t - off] : 0;
            __syncthreads();
            tmp[t] += x;
            __syncthreads();
        }
        int incl = tmp[t];
        int excl = incl - v + carry;
        if (i < N) { offsets[i] = excl; cursor[i] = excl; }
        int total = tmp[1023];
        __syncthreads();   // protect tmp before next chunk overwrites
        carry += total;
    }
}

// ---- kernel 3: scatter edge ids into CSR slots ----
__global__ void fill_kernel(const int* __restrict__ dst, int* __restrict__ cursor,
                            int* __restrict__ csr, int E) {
    int e = blockIdx.x * blockDim.x + threadIdx.x;
    if (e < E) {
        int pos = atomicAdd(&cursor[dst[e]], 1);
        csr[pos] = e;
    }
}

// ---- kernel 4: Wc = Wp @ Wu, bc = bp @ Wu ----
__global__ void combine_kernel(const float* __restrict__ Wp, const float* __restrict__ Wu,
                               const float* __restrict__ bp, float* __restrict__ Wc,
                               float* __restrict__ bc) {
    int idx = blockIdx.x * blockDim.x + threadIdx.x;   // 0..4095
    int d = idx >> 6, j = idx & 63;
    float s = 0.f;
    #pragma unroll
    for (int k = 0; k < D; ++k) s = fmaf(Wp[d * D + k], Wu[k * D + j], s);
    Wc[idx] = s;
    if (d == 0) {
        float t = 0.f;
        #pragma unroll
        for (int k = 0; k < D; ++k) t = fmaf(bp[k], Wu[k * D + j], t);
        bc[j] = t;
    }
}

// ---- kernel 5: per-node gather + mean + fused matmul ----
__global__ __launch_bounds__(256) void node_kernel(
        const float* __restrict__ attrs, const int* __restrict__ csr,
        const int* __restrict__ offsets, const int* __restrict__ counts,
        const float* __restrict__ Wc, const float* __restrict__ bc,
        const float* __restrict__ ub, float* __restrict__ out, int N) {
    __shared__ float wlds[D * D];
    __shared__ float blds[D];
    __shared__ float ulds[D];
    int t = threadIdx.x;
    #pragma unroll
    for (int i = t; i < D * D; i += 256) wlds[i] = Wc[i];
    if (t < D) { blds[t] = bc[t]; ulds[t] = ub[t]; }
    __syncthreads();

    int wave = t >> 6, lane = t & 63;
    int n = blockIdx.x * 4 + wave;
    if (n >= N) return;

    int off = offsets[n];
    int cnt = counts[n];

    float sum = 0.f;
    int j = 0;
    // unroll-by-4 gather: independent index loads then independent row loads
    for (; j + 4 <= cnt; j += 4) {
        int e0 = csr[off + j + 0];
        int e1 = csr[off + j + 1];
        int e2 = csr[off + j + 2];
        int e3 = csr[off + j + 3];
        float a0 = attrs[(size_t)e0 * D + lane];
        float a1 = attrs[(size_t)e1 * D + lane];
        float a2 = attrs[(size_t)e2 * D + lane];
        float a3 = attrs[(size_t)e3 * D + lane];
        sum += (a0 + a1) + (a2 + a3);
    }
    for (; j < cnt; ++j) {
        int e = csr[off + j];
        sum += attrs[(size_t)e * D + lane];
    }

    float mean = (cnt > 0) ? sum / (float)cnt : 0.f;
    // out[n][lane] = sum_d mean[d] * Wc[d][lane] + 1[cnt>0]*bc[lane] + ub[lane]
    float acc = ulds[lane] + ((cnt > 0) ? blds[lane] : 0.f);
    #pragma unroll
    for (int d = 0; d < D; ++d) {
        float m = __shfl(mean, d);
        acc = fmaf(m, wlds[d * D + lane], acc);
    }
    out[(size_t)n * D + lane] = acc;
}

extern "C" void kernel_launch(void* const* d_in, const int* in_sizes, int n_in,
                              void* d_out, int out_size, void* d_ws, size_t ws_size,
                              hipStream_t stream) {
    const float* edge_attrs = (const float*)d_in[0];
    const float* proj_W     = (const float*)d_in[1];
    const float* proj_b     = (const float*)d_in[2];
    const float* upd_W      = (const float*)d_in[3];
    const float* upd_b      = (const float*)d_in[4];
    const int*   dst        = (const int*)d_in[5];

    const int E = in_sizes[0] / D;
    const int N = out_size / D;

    // ws layout
    int*   counts  = (int*)d_ws;
    int*   offsets = counts + N;
    int*   cursor  = offsets + N;
    int*   csr     = cursor + N;
    float* Wc      = (float*)(csr + E);
    float* bc      = Wc + D * D;

    hipMemsetAsync(counts, 0, (size_t)N * sizeof(int), stream);

    int blocks_e = (E + 255) / 256;
    count_kernel<<<blocks_e, 256, 0, stream>>>(dst, counts, E);
    scan_kernel<<<1, 1024, 0, stream>>>(counts, offsets, cursor, N);
    fill_kernel<<<blocks_e, 256, 0, stream>>>(dst, cursor, csr, E);
    combine_kernel<<<16, 256, 0, stream>>>(proj_W, upd_W, proj_b, Wc, bc);

    int blocks_n = (N + 3) / 4;
    node_kernel<<<blocks_n, 256, 0, stream>>>(edge_attrs, csr, offsets, counts,
                                              Wc, bc, upd_b, (float*)d_out, N);
}

// Round 2
// 211.443 us; speedup vs baseline: 1.2141x; 1.2141x over previous
//
#include <hip/hip_runtime.h>
#include <hip/hip_bf16.h>

#define D 64

// ---- kernel 0: zero counts ----
__global__ void zero_kernel(int* __restrict__ p, int n) {
    int i = blockIdx.x * blockDim.x + threadIdx.x;
    if (i < n) p[i] = 0;
}

// ---- kernel 1: histogram counts[dst[e]]++ ----
__global__ void count_kernel(const int* __restrict__ dst, int* __restrict__ counts, int E) {
    int e = blockIdx.x * blockDim.x + threadIdx.x;
    if (e < E) atomicAdd(&counts[dst[e]], 1);
}

// ---- kernel 2: single-block exclusive scan (shfl-based, 2 barriers/chunk) ----
__global__ void scan_kernel(const int* __restrict__ counts, int* __restrict__ offsets,
                            int* __restrict__ cursor, int N) {
    __shared__ int wsum[16];
    int t = threadIdx.x;
    int wave = t >> 6, lane = t & 63;
    int carry = 0;
    for (int base = 0; base < N; base += 1024) {
        int i = base + t;
        int v = (i < N) ? counts[i] : 0;
        // wave-level inclusive scan (no barriers)
        int s = v;
        #pragma unroll
        for (int off = 1; off < 64; off <<= 1) {
            int x = __shfl_up(s, off);
            if (lane >= off) s += x;
        }
        if (lane == 63) wsum[wave] = s;
        __syncthreads();
        int wbase = 0, total = 0;
        #pragma unroll
        for (int w = 0; w < 16; ++w) {
            int x = wsum[w];
            total += x;
            if (w < wave) wbase += x;
        }
        int incl = s + wbase + carry;
        int excl = incl - v;
        if (i < N) { offsets[i] = excl; cursor[i] = excl; }
        carry += total;
        __syncthreads();   // protect wsum before next chunk
    }
    if (t == 0) offsets[N] = carry;   // == E
}

// ---- kernel 3: scatter edge ids into CSR slots ----
__global__ void fill_kernel(const int* __restrict__ dst, int* __restrict__ cursor,
                            int* __restrict__ csr, int E) {
    int e = blockIdx.x * blockDim.x + threadIdx.x;
    if (e < E) {
        int pos = atomicAdd(&cursor[dst[e]], 1);
        csr[pos] = e;
    }
}

// ---- kernel 4: Wc = Wp @ Wu, bc = bp @ Wu ----
__global__ void combine_kernel(const float* __restrict__ Wp, const float* __restrict__ Wu,
                               const float* __restrict__ bp, float* __restrict__ Wc,
                               float* __restrict__ bc) {
    int idx = blockIdx.x * blockDim.x + threadIdx.x;   // 0..4095
    int d = idx >> 6, j = idx & 63;
    float s = 0.f;
    #pragma unroll
    for (int k = 0; k < D; ++k) s = fmaf(Wp[d * D + k], Wu[k * D + j], s);
    Wc[idx] = s;
    if (d == 0) {
        float t = 0.f;
        #pragma unroll
        for (int k = 0; k < D; ++k) t = fmaf(bp[k], Wu[k * D + j], t);
        bc[j] = t;
    }
}

// ---- kernel 5: per-node gather + mean + fused matmul ----
__global__ __launch_bounds__(256) void node_kernel(
        const float* __restrict__ attrs, const int* __restrict__ csr,
        const int* __restrict__ offsets,
        const float* __restrict__ Wc, const float* __restrict__ bc,
        const float* __restrict__ ub, float* __restrict__ out, int N) {
    __shared__ float wlds[D * D];
    __shared__ float blds[D];
    __shared__ float ulds[D];
    int t = threadIdx.x;
    #pragma unroll
    for (int i = t; i < D * D; i += 256) wlds[i] = Wc[i];
    if (t < D) { blds[t] = bc[t]; ulds[t] = ub[t]; }
    __syncthreads();

    int wave = t >> 6, lane = t & 63;
    int n = blockIdx.x * 4 + wave;
    if (n >= N) return;

    int off = offsets[n];
    int cnt = offsets[n + 1] - off;

    float sum = 0.f;
    for (int base = 0; base < cnt; base += 64) {
        int m = cnt - base; if (m > 64) m = 64;
        // cooperative coalesced index load: one 256B load covers up to 64 edges
        int idxv = (lane < m) ? csr[off + base + lane] : 0;
        int jj = 0;
        for (; jj + 8 <= m; jj += 8) {
            int e0 = __shfl(idxv, jj + 0);
            int e1 = __shfl(idxv, jj + 1);
            int e2 = __shfl(idxv, jj + 2);
            int e3 = __shfl(idxv, jj + 3);
            int e4 = __shfl(idxv, jj + 4);
            int e5 = __shfl(idxv, jj + 5);
            int e6 = __shfl(idxv, jj + 6);
            int e7 = __shfl(idxv, jj + 7);
            float a0 = attrs[(size_t)e0 * D + lane];
            float a1 = attrs[(size_t)e1 * D + lane];
            float a2 = attrs[(size_t)e2 * D + lane];
            float a3 = attrs[(size_t)e3 * D + lane];
            float a4 = attrs[(size_t)e4 * D + lane];
            float a5 = attrs[(size_t)e5 * D + lane];
            float a6 = attrs[(size_t)e6 * D + lane];
            float a7 = attrs[(size_t)e7 * D + lane];
            sum += ((a0 + a1) + (a2 + a3)) + ((a4 + a5) + (a6 + a7));
        }
        for (; jj < m; ++jj) {
            int e = __shfl(idxv, jj);
            sum += attrs[(size_t)e * D + lane];
        }
    }

    float mean = (cnt > 0) ? sum / (float)cnt : 0.f;
    float acc = ulds[lane] + ((cnt > 0) ? blds[lane] : 0.f);
    #pragma unroll
    for (int d = 0; d < D; ++d) {
        float m = __shfl(mean, d);
        acc = fmaf(m, wlds[d * D + lane], acc);
    }
    out[(size_t)n * D + lane] = acc;
}

extern "C" void kernel_launch(void* const* d_in, const int* in_sizes, int n_in,
                              void* d_out, int out_size, void* d_ws, size_t ws_size,
                              hipStream_t stream) {
    const float* edge_attrs = (const float*)d_in[0];
    const float* proj_W     = (const float*)d_in[1];
    const float* proj_b     = (const float*)d_in[2];
    const float* upd_W      = (const float*)d_in[3];
    const float* upd_b      = (const float*)d_in[4];
    const int*   dst        = (const int*)d_in[5];

    const int E = in_sizes[0] / D;
    const int N = out_size / D;

    // ws layout
    int*   counts  = (int*)d_ws;
    int*   offsets = counts + N;          // N+1 entries
    int*   cursor  = offsets + N + 1;
    int*   csr     = cursor + N;
    float* Wc      = (float*)(csr + E);
    float* bc      = Wc + D * D;

    zero_kernel<<<(N + 255) / 256, 256, 0, stream>>>(counts, N);

    int blocks_e = (E + 255) / 256;
    count_kernel<<<blocks_e, 256, 0, stream>>>(dst, counts, E);
    scan_kernel<<<1, 1024, 0, stream>>>(counts, offsets, cursor, N);
    fill_kernel<<<blocks_e, 256, 0, stream>>>(dst, cursor, csr, E);
    combine_kernel<<<16, 256, 0, stream>>>(proj_W, upd_W, proj_b, Wc, bc);

    int blocks_n = (N + 3) / 4;
    node_kernel<<<blocks_n, 256, 0, stream>>>(edge_attrs, csr, offsets,
                                              Wc, bc, upd_b, (float*)d_out, N);
}

// Round 3
// 171.318 us; speedup vs baseline: 1.4985x; 1.2342x over previous
//
#include <hip/hip_runtime.h>
#include <hip/hip_bf16.h>

#define D 64

// ---- kernel 0: zero counts ----
__global__ void zero_kernel(int* __restrict__ p, int n) {
    int i = blockIdx.x * blockDim.x + threadIdx.x;
    if (i < n) p[i] = 0;
}

// ---- kernel 1: histogram counts[dst[e]]++ ----
__global__ void count_kernel(const int* __restrict__ dst, int* __restrict__ counts, int E) {
    int e = blockIdx.x * blockDim.x + threadIdx.x;
    if (e < E) atomicAdd(&counts[dst[e]], 1);
}

// ---- kernel 2a: per-block sums of counts (256/block) ----
__global__ void blocksum_kernel(const int* __restrict__ counts, int* __restrict__ bsums, int N) {
    int t = threadIdx.x;
    int i = blockIdx.x * 256 + t;
    int v = (i < N) ? counts[i] : 0;
    int lane = t & 63, wave = t >> 6;
    #pragma unroll
    for (int o = 1; o < 64; o <<= 1) v += __shfl_xor(v, o);
    __shared__ int ws[4];
    if (lane == 0) ws[wave] = v;
    __syncthreads();
    if (t == 0) bsums[blockIdx.x] = ws[0] + ws[1] + ws[2] + ws[3];
}

// ---- kernel 2b: single-block exclusive scan of block sums (nb <= 1024) ----
__global__ void blockscan_kernel(const int* __restrict__ bsums, int* __restrict__ boffs,
                                 int* __restrict__ offsets, int N, int nb) {
    __shared__ int wsum[16];
    int t = threadIdx.x;
    int wave = t >> 6, lane = t & 63;
    int v = (t < nb) ? bsums[t] : 0;
    int s = v;
    #pragma unroll
    for (int off = 1; off < 64; off <<= 1) {
        int x = __shfl_up(s, off);
        if (lane >= off) s += x;
    }
    if (lane == 63) wsum[wave] = s;
    __syncthreads();
    int wbase = 0, total = 0;
    #pragma unroll
    for (int w = 0; w < 16; ++w) {
        int x = wsum[w];
        total += x;
        if (w < wave) wbase += x;
    }
    if (t < nb) boffs[t] = s - v + wbase;
    if (t == 0) offsets[N] = total;   // == E
}

// ---- kernel 2c: per-block exclusive scan + block offset -> offsets, cursor ----
__global__ void scatter_scan_kernel(const int* __restrict__ counts, const int* __restrict__ boffs,
                                    int* __restrict__ offsets, int* __restrict__ cursor, int N) {
    int t = threadIdx.x;
    int i = blockIdx.x * 256 + t;
    int v = (i < N) ? counts[i] : 0;
    int lane = t & 63, wave = t >> 6;
    int s = v;
    #pragma unroll
    for (int off = 1; off < 64; off <<= 1) {
        int x = __shfl_up(s, off);
        if (lane >= off) s += x;
    }
    __shared__ int ws[4];
    if (lane == 63) ws[wave] = s;
    __syncthreads();
    int wbase = 0;
    #pragma unroll
    for (int w = 0; w < 4; ++w) if (w < wave) wbase += ws[w];
    int excl = s - v + wbase + boffs[blockIdx.x];
    if (i < N) { offsets[i] = excl; cursor[i] = excl; }
}

// ---- kernel 3: scatter edge ids into CSR slots ----
__global__ void fill_kernel(const int* __restrict__ dst, int* __restrict__ cursor,
                            int* __restrict__ csr, int E) {
    int e = blockIdx.x * blockDim.x + threadIdx.x;
    if (e < E) {
        int pos = atomicAdd(&cursor[dst[e]], 1);
        csr[pos] = e;
    }
}

// ---- kernel 4: Wc = Wp @ Wu, bc = bp @ Wu ----
__global__ void combine_kernel(const float* __restrict__ Wp, const float* __restrict__ Wu,
                               const float* __restrict__ bp, float* __restrict__ Wc,
                               float* __restrict__ bc) {
    int idx = blockIdx.x * blockDim.x + threadIdx.x;   // 0..4095
    int d = idx >> 6, j = idx & 63;
    float s = 0.f;
    #pragma unroll
    for (int k = 0; k < D; ++k) s = fmaf(Wp[d * D + k], Wu[k * D + j], s);
    Wc[idx] = s;
    if (d == 0) {
        float t = 0.f;
        #pragma unroll
        for (int k = 0; k < D; ++k) t = fmaf(bp[k], Wu[k * D + j], t);
        bc[j] = t;
    }
}

// ---- kernel 5: per-node gather (float4, 4 edges in flight) + mean + fused matmul ----
__global__ __launch_bounds__(256) void node_kernel(
        const float4* __restrict__ attrs4, const int* __restrict__ csr,
        const int* __restrict__ offsets,
        const float* __restrict__ Wc, const float* __restrict__ bc,
        const float* __restrict__ ub, float* __restrict__ out, int N) {
    __shared__ float wlds[D * D];
    __shared__ float blds[D];
    __shared__ float ulds[D];
    int t = threadIdx.x;
    #pragma unroll
    for (int i = t; i < D * D; i += 256) wlds[i] = Wc[i];
    if (t < D) { blds[t] = bc[t]; ulds[t] = ub[t]; }
    __syncthreads();

    int wave = t >> 6, lane = t & 63;
    int n = blockIdx.x * 4 + wave;
    if (n >= N) return;

    int off = offsets[n];
    int cnt = offsets[n + 1] - off;

    int g = lane >> 4;      // edge subgroup 0..3
    int q = lane & 15;      // quarter-row (float4 index within row)

    float4 acc = make_float4(0.f, 0.f, 0.f, 0.f);
    for (int base = 0; base < cnt; base += 64) {
        int m = cnt - base; if (m > 64) m = 64;
        // cooperative coalesced index load: one 256B load covers up to 64 edges
        int idxv = (lane < m) ? csr[off + base + lane] : 0;
        for (int jj = 0; jj < m; jj += 4) {
            int sel = jj + g;                 // <= 63 always
            int e = __shfl(idxv, sel);
            if (sel < m) {
                float4 a = attrs4[(size_t)e * 16 + q];
                acc.x += a.x; acc.y += a.y; acc.z += a.z; acc.w += a.w;
            }
        }
    }
    // reduce across the 4 edge subgroups (lanes differing in bits 4,5)
    acc.x += __shfl_xor(acc.x, 16); acc.y += __shfl_xor(acc.y, 16);
    acc.z += __shfl_xor(acc.z, 16); acc.w += __shfl_xor(acc.w, 16);
    acc.x += __shfl_xor(acc.x, 32); acc.y += __shfl_xor(acc.y, 32);
    acc.z += __shfl_xor(acc.z, 32); acc.w += __shfl_xor(acc.w, 32);

    float inv = (cnt > 0) ? 1.f / (float)cnt : 0.f;
    float marr[4] = { acc.x * inv, acc.y * inv, acc.z * inv, acc.w * inv };
    // lane q holds mean[4q..4q+3] (duplicated across groups; we read lanes 0..15)

    float accO = ulds[lane] + ((cnt > 0) ? blds[lane] : 0.f);
    #pragma unroll
    for (int d = 0; d < D; ++d) {
        float mv = __shfl(marr[d & 3], d >> 2);
        accO = fmaf(mv, wlds[d * D + lane], accO);
    }
    out[(size_t)n * D + lane] = accO;
}

extern "C" void kernel_launch(void* const* d_in, const int* in_sizes, int n_in,
                              void* d_out, int out_size, void* d_ws, size_t ws_size,
                              hipStream_t stream) {
    const float* edge_attrs = (const float*)d_in[0];
    const float* proj_W     = (const float*)d_in[1];
    const float* proj_b     = (const float*)d_in[2];
    const float* upd_W      = (const float*)d_in[3];
    const float* upd_b      = (const float*)d_in[4];
    const int*   dst        = (const int*)d_in[5];

    const int E = in_sizes[0] / D;
    const int N = out_size / D;
    const int nb = (N + 255) / 256;   // blocks for two-level scan (196 for N=50000)

    // ws layout
    int*   counts  = (int*)d_ws;
    int*   offsets = counts + N;          // N+1 entries
    int*   cursor  = offsets + N + 1;
    int*   bsums   = cursor + N;
    int*   boffs   = bsums + nb;
    int*   csr     = boffs + nb;
    float* Wc      = (float*)(csr + E);
    float* bc      = Wc + D * D;

    zero_kernel<<<(N + 255) / 256, 256, 0, stream>>>(counts, N);

    int blocks_e = (E + 255) / 256;
    count_kernel<<<blocks_e, 256, 0, stream>>>(dst, counts, E);
    blocksum_kernel<<<nb, 256, 0, stream>>>(counts, bsums, N);
    blockscan_kernel<<<1, 1024, 0, stream>>>(bsums, boffs, offsets, N, nb);
    scatter_scan_kernel<<<nb, 256, 0, stream>>>(counts, boffs, offsets, cursor, N);
    fill_kernel<<<blocks_e, 256, 0, stream>>>(dst, cursor, csr, E);
    combine_kernel<<<16, 256, 0, stream>>>(proj_W, upd_W, proj_b, Wc, bc);

    int blocks_n = (N + 3) / 4;
    node_kernel<<<blocks_n, 256, 0, stream>>>((const float4*)edge_attrs, csr, offsets,
                                              Wc, bc, upd_b, (float*)d_out, N);
}

// Round 4
// 170.834 us; speedup vs baseline: 1.5027x; 1.0028x over previous
//
#include <hip/hip_runtime.h>
#include <hip/hip_bf16.h>

#define D 64

// ---- kernel 0: zero counts (int4) ----
__global__ void zero_kernel(int4* __restrict__ p, int n4) {
    int i = blockIdx.x * blockDim.x + threadIdx.x;
    if (i < n4) p[i] = make_int4(0, 0, 0, 0);
}

// ---- kernel 1: histogram counts[dst[e]]++ (int4 reads) ----
__global__ void count_kernel(const int4* __restrict__ dst4, int* __restrict__ counts, int E4) {
    int i = blockIdx.x * blockDim.x + threadIdx.x;
    if (i < E4) {
        int4 d = dst4[i];
        atomicAdd(&counts[d.x], 1);
        atomicAdd(&counts[d.y], 1);
        atomicAdd(&counts[d.z], 1);
        atomicAdd(&counts[d.w], 1);
    }
}

// ---- kernel 2a: per-block sums of counts (256/block) ----
__global__ void blocksum_kernel(const int* __restrict__ counts, int* __restrict__ bsums, int N) {
    int t = threadIdx.x;
    int i = blockIdx.x * 256 + t;
    int v = (i < N) ? counts[i] : 0;
    int lane = t & 63, wave = t >> 6;
    #pragma unroll
    for (int o = 1; o < 64; o <<= 1) v += __shfl_xor(v, o);
    __shared__ int ws[4];
    if (lane == 0) ws[wave] = v;
    __syncthreads();
    if (t == 0) bsums[blockIdx.x] = ws[0] + ws[1] + ws[2] + ws[3];
}

// ---- kernel 2b: single-block exclusive scan of block sums + fused Wc/bc combine ----
__global__ void blockscan_kernel(const int* __restrict__ bsums, int* __restrict__ boffs,
                                 int* __restrict__ offsets, int N, int nb,
                                 const float* __restrict__ Wp, const float* __restrict__ Wu,
                                 const float* __restrict__ bp,
                                 float* __restrict__ Wc, float* __restrict__ bc) {
    __shared__ int wsum[16];
    int t = threadIdx.x;
    int wave = t >> 6, lane = t & 63;
    int v = (t < nb) ? bsums[t] : 0;
    int s = v;
    #pragma unroll
    for (int off = 1; off < 64; off <<= 1) {
        int x = __shfl_up(s, off);
        if (lane >= off) s += x;
    }
    if (lane == 63) wsum[wave] = s;
    __syncthreads();
    int wbase = 0, total = 0;
    #pragma unroll
    for (int w = 0; w < 16; ++w) {
        int x = wsum[w];
        total += x;
        if (w < wave) wbase += x;
    }
    if (t < nb) boffs[t] = s - v + wbase;
    if (t == 0) offsets[N] = total;   // == E

    // ---- fused combine: Wc = Wp @ Wu, bc = bp @ Wu ----
    for (int idx = t; idx < D * D; idx += 1024) {
        int d = idx >> 6, j = idx & 63;
        float acc = 0.f;
        #pragma unroll
        for (int k = 0; k < D; ++k) acc = fmaf(Wp[d * D + k], Wu[k * D + j], acc);
        Wc[idx] = acc;
    }
    if (t < D) {
        float acc = 0.f;
        #pragma unroll
        for (int k = 0; k < D; ++k) acc = fmaf(bp[k], Wu[k * D + t], acc);
        bc[t] = acc;
    }
}

// ---- kernel 2c: per-block exclusive scan + block offset -> offsets, cursor ----
__global__ void scatter_scan_kernel(const int* __restrict__ counts, const int* __restrict__ boffs,
                                    int* __restrict__ offsets, int* __restrict__ cursor, int N) {
    int t = threadIdx.x;
    int i = blockIdx.x * 256 + t;
    int v = (i < N) ? counts[i] : 0;
    int lane = t & 63, wave = t >> 6;
    int s = v;
    #pragma unroll
    for (int off = 1; off < 64; off <<= 1) {
        int x = __shfl_up(s, off);
        if (lane >= off) s += x;
    }
    __shared__ int ws[4];
    if (lane == 63) ws[wave] = s;
    __syncthreads();
    int wbase = 0;
    #pragma unroll
    for (int w = 0; w < 4; ++w) if (w < wave) wbase += ws[w];
    int excl = s - v + wbase + boffs[blockIdx.x];
    if (i < N) { offsets[i] = excl; cursor[i] = excl; }
}

// ---- kernel 3: scatter edge ids into CSR slots (int4 reads) ----
__global__ void fill_kernel(const int4* __restrict__ dst4, int* __restrict__ cursor,
                            int* __restrict__ csr, int E4) {
    int i = blockIdx.x * blockDim.x + threadIdx.x;
    if (i < E4) {
        int4 d = dst4[i];
        int e = i * 4;
        csr[atomicAdd(&cursor[d.x], 1)] = e + 0;
        csr[atomicAdd(&cursor[d.y], 1)] = e + 1;
        csr[atomicAdd(&cursor[d.z], 1)] = e + 2;
        csr[atomicAdd(&cursor[d.w], 1)] = e + 3;
    }
}

// ---- kernel 5: per-node gather (float4, 8 edges in flight) + mean + fused matmul ----
__global__ __launch_bounds__(256) void node_kernel(
        const float4* __restrict__ attrs4, const int* __restrict__ csr,
        const int* __restrict__ offsets,
        const float* __restrict__ Wc, const float* __restrict__ bc,
        const float* __restrict__ ub, float* __restrict__ out, int N) {
    __shared__ float wlds[D * D];
    __shared__ float blds[D];
    __shared__ float ulds[D];
    __shared__ int soff[5];
    int t = threadIdx.x;
    int nbase = blockIdx.x * 4;
    if (t < 5) {
        int nn = nbase + t;
        soff[t] = offsets[(nn <= N) ? nn : N];
    }
    #pragma unroll
    for (int i = t; i < D * D; i += 256) wlds[i] = Wc[i];
    if (t < D) { blds[t] = bc[t]; ulds[t] = ub[t]; }
    __syncthreads();

    int wave = t >> 6, lane = t & 63;
    int n = nbase + wave;
    if (n >= N) return;

    int off = soff[wave];
    int cnt = soff[wave + 1] - off;

    int g = lane >> 4;      // edge subgroup 0..3
    int q = lane & 15;      // quarter-row (float4 index within row)

    float4 acc0 = make_float4(0.f, 0.f, 0.f, 0.f);
    float4 acc1 = make_float4(0.f, 0.f, 0.f, 0.f);
    for (int base = 0; base < cnt; base += 64) {
        int m = cnt - base; if (m > 64) m = 64;
        // cooperative coalesced index load: one 256B load covers up to 64 edges
        int idxv = (lane < m) ? csr[off + base + lane] : 0;
        int jj = 0;
        for (; jj + 8 <= m; jj += 8) {
            int e0 = __shfl(idxv, jj + g);
            int e1 = __shfl(idxv, jj + 4 + g);
            float4 a0 = attrs4[(size_t)e0 * 16 + q];
            float4 a1 = attrs4[(size_t)e1 * 16 + q];
            acc0.x += a0.x; acc0.y += a0.y; acc0.z += a0.z; acc0.w += a0.w;
            acc1.x += a1.x; acc1.y += a1.y; acc1.z += a1.z; acc1.w += a1.w;
        }
        for (; jj < m; jj += 4) {
            int sel = jj + g;
            int e = __shfl(idxv, sel);
            if (sel < m) {
                float4 a = attrs4[(size_t)e * 16 + q];
                acc0.x += a.x; acc0.y += a.y; acc0.z += a.z; acc0.w += a.w;
            }
        }
    }
    float4 acc = make_float4(acc0.x + acc1.x, acc0.y + acc1.y,
                             acc0.z + acc1.z, acc0.w + acc1.w);
    // reduce across the 4 edge subgroups (lanes differing in bits 4,5)
    acc.x += __shfl_xor(acc.x, 16); acc.y += __shfl_xor(acc.y, 16);
    acc.z += __shfl_xor(acc.z, 16); acc.w += __shfl_xor(acc.w, 16);
    acc.x += __shfl_xor(acc.x, 32); acc.y += __shfl_xor(acc.y, 32);
    acc.z += __shfl_xor(acc.z, 32); acc.w += __shfl_xor(acc.w, 32);

    float inv = (cnt > 0) ? 1.f / (float)cnt : 0.f;
    float marr[4] = { acc.x * inv, acc.y * inv, acc.z * inv, acc.w * inv };
    // lane q holds mean[4q..4q+3] (duplicated across groups; we read lanes 0..15)

    float accO = ulds[lane] + ((cnt > 0) ? blds[lane] : 0.f);
    #pragma unroll
    for (int d = 0; d < D; ++d) {
        float mv = __shfl(marr[d & 3], d >> 2);
        accO = fmaf(mv, wlds[d * D + lane], accO);
    }
    out[(size_t)n * D + lane] = accO;
}

extern "C" void kernel_launch(void* const* d_in, const int* in_sizes, int n_in,
                              void* d_out, int out_size, void* d_ws, size_t ws_size,
                              hipStream_t stream) {
    const float* edge_attrs = (const float*)d_in[0];
    const float* proj_W     = (const float*)d_in[1];
    const float* proj_b     = (const float*)d_in[2];
    const float* upd_W      = (const float*)d_in[3];
    const float* upd_b      = (const float*)d_in[4];
    const int*   dst        = (const int*)d_in[5];

    const int E = in_sizes[0] / D;
    const int N = out_size / D;
    const int nb = (N + 255) / 256;   // blocks for two-level scan (196 for N=50000)
    const int E4 = E / 4;             // E=800000 divisible by 4
    const int N4 = N / 4;

    // ws layout
    int*   counts  = (int*)d_ws;
    int*   offsets = counts + N;          // N+1 entries
    int*   cursor  = offsets + N + 1;
    int*   bsums   = cursor + N;
    int*   boffs   = bsums + nb;
    int*   csr     = boffs + nb;
    float* Wc      = (float*)(csr + E);
    float* bc      = Wc + D * D;

    zero_kernel<<<(N4 + 255) / 256, 256, 0, stream>>>((int4*)counts, N4);
    count_kernel<<<(E4 + 255) / 256, 256, 0, stream>>>((const int4*)dst, counts, E4);
    blocksum_kernel<<<nb, 256, 0, stream>>>(counts, bsums, N);
    blockscan_kernel<<<1, 1024, 0, stream>>>(bsums, boffs, offsets, N, nb,
                                             proj_W, upd_W, proj_b, Wc, bc);
    scatter_scan_kernel<<<nb, 256, 0, stream>>>(counts, boffs, offsets, cursor, N);
    fill_kernel<<<(E4 + 255) / 256, 256, 0, stream>>>((const int4*)dst, cursor, csr, E4);

    int blocks_n = (N + 3) / 4;
    node_kernel<<<blocks_n, 256, 0, stream>>>((const float4*)edge_attrs, csr, offsets,
                                              Wc, bc, upd_b, (float*)d_out, N);
}